// Round 3
// baseline (1338.078 us; speedup 1.0000x reference)
//
#include <hip/hip_runtime.h>
#include <math.h>

#define S_TOT 2048
#define B_    64
#define E_    256
#define H_    256

typedef __fp16 half2v __attribute__((ext_vector_type(2)));

__device__ __forceinline__ float dpp_xor1(float x) {
    int i = __builtin_bit_cast(int, x);
    i = __builtin_amdgcn_mov_dpp(i, 0xB1, 0xF, 0xF, true);   // quad_perm [1,0,3,2]
    return __builtin_bit_cast(float, i);
}
__device__ __forceinline__ float dpp_xor2(float x) {
    int i = __builtin_bit_cast(int, x);
    i = __builtin_amdgcn_mov_dpp(i, 0x4E, 0xF, 0xF, true);   // quad_perm [2,3,0,1]
    return __builtin_bit_cast(float, i);
}

// Fused kernel: blocks [0, scan_blocks) run the sequential scan (one block per
// batch, 512 threads); blocks [scan_blocks, grid) run the xp GEMM for the NEXT
// chunk. Kernel boundary = producer->consumer sync between chunks.
//
// Scan split: ks = tid&3 (k-range of 64), jg = tid>>2 (outputs 2jg, 2jg+1).
// Cross-lane reduce = 2 rounds of DPP quad_perm (VALU only).
//
// w residency: R0-R2 allocated only 48-88 VGPRs -> the compiler was re-loading
// the 64 Whh half2 values EVERY step (remat/scratch) on the serial critical
// path. Fix: 64 individually-named ints (no aggregate), each pinned by asm,
// plus amdgpu_waves_per_eu(2,2) so the allocator targets exactly 2 waves/EU
// (VGPR budget 256) instead of squeezing for 8-wave occupancy.
__global__ __launch_bounds__(512)
__attribute__((amdgpu_waves_per_eu(2, 2)))
void fused_step(
    const float* __restrict__ A,       // sentence chunk for gemm [Mc, E] (or null)
    const float* __restrict__ Wih,     // [E, H]
    const float* __restrict__ bias,    // [H]
    float*       __restrict__ xp_next, // [chunk*B, H] gemm output
    const float* __restrict__ xp_cur,  // [steps, B, H] scan input
    const float* __restrict__ Whh,     // [H, H]
    float*       __restrict__ h,       // [B, H] persistent state (= d_out)
    int steps, int scan_blocks)
{
    __shared__ float smem[32 * 68 + 32 * 64];   // gemm tiles; scan reuses front
    const int tid = threadIdx.x;

    if ((int)blockIdx.x < scan_blocks) {
        // ------------- scan: h_new = tanh(xp + h @ Whh), 512 threads ---------
        // h ping-pong in LDS: 4 segments of 64 f16 (32 dwords) + 4-dword pad,
        // segment stride 36 dwords -> ks*36 mod 32 = {0,4,8,12}: the 4
        // broadcast groups of a wave read disjoint bank quads (conflict-free).
        float* hbuf = smem;              // [2][4][36] dwords
        const int b  = blockIdx.x;
        const int ks = tid & 3;          // k-range [ks*64, ks*64+64)
        const int jg = tid >> 2;         // 0..127 -> outputs 2jg, 2jg+1
        const int j0 = jg << 1;
        const int jf = j0 + (ks & 1);    // output this lane holds post-reduce

        // w<i>_<jj> = (Whh[ks*64+2i][j0+jj], Whh[ks*64+2i+1][j0+jj]) as f16x2,
        // held in 64 named VGPRs for the whole scan.
#define DECLW(i) int w##i##_0, w##i##_1;
        DECLW(0)  DECLW(1)  DECLW(2)  DECLW(3)  DECLW(4)  DECLW(5)  DECLW(6)  DECLW(7)
        DECLW(8)  DECLW(9)  DECLW(10) DECLW(11) DECLW(12) DECLW(13) DECLW(14) DECLW(15)
        DECLW(16) DECLW(17) DECLW(18) DECLW(19) DECLW(20) DECLW(21) DECLW(22) DECLW(23)
        DECLW(24) DECLW(25) DECLW(26) DECLW(27) DECLW(28) DECLW(29) DECLW(30) DECLW(31)

#define LOADW(i) { \
        const float* r0_ = &Whh[(size_t)(ks * 64 + 2 * i) * H_ + j0]; \
        const float* r1_ = r0_ + H_; \
        half2v v0_ = __builtin_amdgcn_cvt_pkrtz(r0_[0], r1_[0]); \
        half2v v1_ = __builtin_amdgcn_cvt_pkrtz(r0_[1], r1_[1]); \
        w##i##_0 = __builtin_bit_cast(int, v0_); \
        w##i##_1 = __builtin_bit_cast(int, v1_); \
        asm volatile("" : "+v"(w##i##_0), "+v"(w##i##_1)); \
    }
        LOADW(0)  LOADW(1)  LOADW(2)  LOADW(3)  LOADW(4)  LOADW(5)  LOADW(6)  LOADW(7)
        LOADW(8)  LOADW(9)  LOADW(10) LOADW(11) LOADW(12) LOADW(13) LOADW(14) LOADW(15)
        LOADW(16) LOADW(17) LOADW(18) LOADW(19) LOADW(20) LOADW(21) LOADW(22) LOADW(23)
        LOADW(24) LOADW(25) LOADW(26) LOADW(27) LOADW(28) LOADW(29) LOADW(30) LOADW(31)

        if (tid < 128) {
            half2v hp = __builtin_amdgcn_cvt_pkrtz(h[b * H_ + 2 * tid],
                                                   h[b * H_ + 2 * tid + 1]);
            // j = 2*tid: segment tid>>5, dword offset tid&31
            ((half2v*)hbuf)[(tid >> 5) * 36 + (tid & 31)] = hp;
        }
        float xpn = xp_cur[(size_t)b * H_ + jf];
        __syncthreads();

        int p = 0;
        const int rd_base = ks * 36;                 // dwords
        const int wr_idx  = (jg >> 5) * 36 + (jg & 31);  // half2 slot (ks==0 lanes)
        for (int s = 0; s < steps; s++) {
            const float xpc = xpn;
            if (s + 1 < steps)
                xpn = xp_cur[((size_t)(s + 1) * B_ + b) * H_ + jf];

            // this lane's 64-value h segment: 8 x ds_read_b128 (broadcast x16)
            half2v hk[32];
            {
                const float4* hs = (const float4*)&hbuf[p * 144 + rd_base];
                #pragma unroll
                for (int t = 0; t < 8; t++)
                    *(float4*)&hk[t * 4] = hs[t];
            }

            // 64 fdot2, 4 partial chains of depth 16
            float p00 = 0.f, p01 = 0.f, p10 = 0.f, p11 = 0.f;
#define DOTA(i) \
            p00 = __builtin_amdgcn_fdot2(hk[i], __builtin_bit_cast(half2v, w##i##_0), p00, false); \
            p01 = __builtin_amdgcn_fdot2(hk[i], __builtin_bit_cast(half2v, w##i##_1), p01, false);
#define DOTB(i) \
            p10 = __builtin_amdgcn_fdot2(hk[i], __builtin_bit_cast(half2v, w##i##_0), p10, false); \
            p11 = __builtin_amdgcn_fdot2(hk[i], __builtin_bit_cast(half2v, w##i##_1), p11, false);
            DOTA(0)  DOTA(1)  DOTA(2)  DOTA(3)  DOTA(4)  DOTA(5)  DOTA(6)  DOTA(7)
            DOTA(8)  DOTA(9)  DOTA(10) DOTA(11) DOTA(12) DOTA(13) DOTA(14) DOTA(15)
            DOTB(16) DOTB(17) DOTB(18) DOTB(19) DOTB(20) DOTB(21) DOTB(22) DOTB(23)
            DOTB(24) DOTB(25) DOTB(26) DOTB(27) DOTB(28) DOTB(29) DOTB(30) DOTB(31)

            const float acc0 = p00 + p10;            // partial(j0,   k-range ks)
            const float acc1 = p01 + p11;            // partial(j0+1, k-range ks)

            // split-butterfly over the 4 ks lanes, all DPP quad_perm:
            const bool b0 = (ks & 1);
            const float r = (b0 ? acc1 : acc0) + dpp_xor1(b0 ? acc0 : acc1);
            const float v = r + dpp_xor2(r) + xpc;

            const float e2 = __expf(2.f * v);
            const float hn = 1.f - 2.f / (e2 + 1.f);   // tanh(v)

            // pack (j0, j0+1) into one half2; single writer per quad (ks==0)
            const float other = dpp_xor1(hn);
            if (ks == 0) {
                ((half2v*)hbuf)[(p ^ 1) * 144 + wr_idx] =
                    __builtin_amdgcn_cvt_pkrtz(hn, other);
                if (s == steps - 1) {                  // fp32 carry-out
                    float2 o; o.x = hn; o.y = other;
                    *(float2*)&h[b * H_ + j0] = o;
                }
            }
            __syncthreads();
            p ^= 1;
        }
    } else if (A != nullptr) {
        // ---------------- gemm: xp_next = A @ Wih + bias (512 threads) -------
        float (*As)[68] = (float(*)[68])smem;
        float (*Bs)[64] = (float(*)[64])(smem + 32 * 68);

        const int gid = blockIdx.x - scan_blocks;
        const int bm = (gid >> 2) * 64;
        const int bn = (gid & 3) * 64;
        const int tx = tid & 15;         // 4 output cols
        const int ty = tid >> 4;         // 0..31 -> 2 output rows

        float acc[2][4] = {};

        const int ar = tid >> 3;         // 0..63
        const int ak = (tid & 7) << 2;   // 0..28
        const int br = tid >> 4;         // 0..31
        const int bc = (tid & 15) << 2;

        for (int k0 = 0; k0 < E_; k0 += 32) {
            float4 a0  = *(const float4*)&A[(size_t)(bm + ar) * E_ + k0 + ak];
            float4 bv0 = *(const float4*)&Wih[(size_t)(k0 + br) * H_ + bn + bc];

            As[ak+0][ar] = a0.x; As[ak+1][ar] = a0.y;
            As[ak+2][ar] = a0.z; As[ak+3][ar] = a0.w;
            *(float4*)&Bs[br][bc] = bv0;
            __syncthreads();

            #pragma unroll
            for (int kk = 0; kk < 32; kk++) {
                const float2 av = *(const float2*)&As[kk][ty << 1];
                const float4 bv = *(const float4*)&Bs[kk][tx << 2];
                acc[0][0] += av.x*bv.x; acc[0][1] += av.x*bv.y;
                acc[0][2] += av.x*bv.z; acc[0][3] += av.x*bv.w;
                acc[1][0] += av.y*bv.x; acc[1][1] += av.y*bv.y;
                acc[1][2] += av.y*bv.z; acc[1][3] += av.y*bv.w;
            }
            __syncthreads();
        }

        const float4 bb = *(const float4*)&bias[bn + (tx << 2)];
        #pragma unroll
        for (int i = 0; i < 2; i++) {
            float4 o;
            o.x = acc[i][0] + bb.x;
            o.y = acc[i][1] + bb.y;
            o.z = acc[i][2] + bb.z;
            o.w = acc[i][3] + bb.w;
            *(float4*)&xp_next[(size_t)(bm + (ty << 1) + i) * H_ + bn + (tx << 2)] = o;
        }
    }
}

extern "C" void kernel_launch(void* const* d_in, const int* in_sizes, int n_in,
                              void* d_out, int out_size, void* d_ws, size_t ws_size,
                              hipStream_t stream)
{
    const float* sentence = (const float*)d_in[0];  // [S,B,E]
    const float* h0       = (const float*)d_in[1];  // [B,H]
    const float* W_ih     = (const float*)d_in[2];  // [E,H]
    const float* W_hh     = (const float*)d_in[3];  // [H,H]
    const float* bias     = (const float*)d_in[4];  // [H]
    float* h  = (float*)d_out;
    float* ws = (float*)d_ws;

    // two ping-pong xp buffers, each [chunk*B, H]
    int chunk = 256;
    while ((size_t)2 * chunk * B_ * H_ * sizeof(float) > ws_size && chunk > 32)
        chunk >>= 1;
    const int nchunk = S_TOT / chunk;
    float* buf[2] = { ws, ws + (size_t)chunk * B_ * H_ };

    hipMemcpyAsync(h, h0, B_ * H_ * sizeof(float), hipMemcpyDeviceToDevice, stream);

    // pure gemm for chunk 0
    fused_step<<<chunk * 4, 512, 0, stream>>>(sentence, W_ih, bias, buf[0],
                                              nullptr, W_hh, h, 0, 0);
    for (int c = 0; c < nchunk; c++) {
        const bool last = (c == nchunk - 1);
        const int gemmb = last ? 0 : chunk * 4;
        const float* Anext = last ? nullptr
                                  : sentence + (size_t)(c + 1) * chunk * B_ * E_;
        fused_step<<<64 + gemmb, 512, 0, stream>>>(Anext, W_ih, bias,
                                                   buf[(c + 1) & 1],
                                                   buf[c & 1], W_hh, h,
                                                   chunk, 64);
    }
}

// Round 5
// 1212.558 us; speedup vs baseline: 1.1035x; 1.1035x over previous
//
#include <hip/hip_runtime.h>
#include <math.h>

#define S_TOT 2048
#define B_    64
#define E_    256
#define H_    256

typedef __fp16 half2v __attribute__((ext_vector_type(2)));

__device__ __forceinline__ float dpp_xor1(float x) {
    int i = __builtin_bit_cast(int, x);
    i = __builtin_amdgcn_mov_dpp(i, 0xB1, 0xF, 0xF, true);   // quad_perm [1,0,3,2]
    return __builtin_bit_cast(float, i);
}
__device__ __forceinline__ float dpp_xor2(float x) {
    int i = __builtin_bit_cast(int, x);
    i = __builtin_amdgcn_mov_dpp(i, 0x4E, 0xF, 0xF, true);   // quad_perm [2,3,0,1]
    return __builtin_bit_cast(float, i);
}
__device__ __forceinline__ int dpp_xor1_i(int i) {
    return __builtin_amdgcn_mov_dpp(i, 0xB1, 0xF, 0xF, true);
}
__device__ __forceinline__ int dpp_xor2_i(int i) {
    return __builtin_amdgcn_mov_dpp(i, 0x4E, 0xF, 0xF, true);
}

// Fused kernel: blocks [0, scan_blocks) run the sequential scan (one block per
// batch, 256 threads = 4 waves); blocks [scan_blocks, grid) run the xp GEMM
// for the NEXT chunk. Kernel boundary = producer->consumer sync between chunks.
//
// R3 post-mortem: per-step floor (~1425 cyc) is dominated by CU-SHARED costs:
// the LDS pipe (72 LDS instrs/step with 8 waves) and the 8-wave barrier —
// not per-wave compute (R2/R3 compute fixes moved <15%). This version halves
// the wave count: ksplit=4, 4 outputs/lane -> 32 ds_read_b128 + 4 ds_write_b64
// per CU per step (was 64+8), 4-wave barrier, same VALU issue per SIMD.
// (R4 bench was an infra failure — container failed twice, no counters;
// resubmitting unchanged.)
__global__ __launch_bounds__(256)
__attribute__((amdgpu_waves_per_eu(1, 1)))
void fused_step(
    const float* __restrict__ A,       // sentence chunk for gemm [Mc, E] (or null)
    const float* __restrict__ Wih,     // [E, H]
    const float* __restrict__ bias,    // [H]
    float*       __restrict__ xp_next, // [chunk*B, H] gemm output
    const float* __restrict__ xp_cur,  // [steps, B, H] scan input
    const float* __restrict__ Whh,     // [H, H]
    float*       __restrict__ h,       // [B, H] persistent state (= d_out)
    int steps, int scan_blocks)
{
    __shared__ float smem[32 * 68 + 32 * 64];   // gemm tiles; scan reuses front
    const int tid = threadIdx.x;

    if ((int)blockIdx.x < scan_blocks) {
        // ------------- scan: h_new = tanh(xp + h @ Whh), 256 threads ---------
        // h ping-pong in LDS: 4 segments of 64 f16 (32 dwords) + 4-dword pad,
        // segment stride 36 dwords -> ks*36 mod 32 = {0,4,8,12}: the 4
        // broadcast groups of a wave read disjoint bank quads (conflict-free).
        float* hbuf = smem;              // [2][4][36] dwords
        const int b  = blockIdx.x;
        const int ks = tid & 3;          // k-range [ks*64, ks*64+64)
        const int jg = tid >> 2;         // 0..63 -> outputs 4jg .. 4jg+3
        const int j0 = jg << 2;
        // output this lane holds after the 2-round split-butterfly:
        const int jf = j0 + ((ks & 1) << 1) + ((ks >> 1) & 1);

        // w<i>_<jj> = (Whh[ks*64+2i][j0+jj], Whh[ks*64+2i+1][j0+jj]) as f16x2,
        // 128 named VGPRs, pinned resident for the whole scan.
#define DECLW(i) int w##i##_0, w##i##_1, w##i##_2, w##i##_3;
        DECLW(0)  DECLW(1)  DECLW(2)  DECLW(3)  DECLW(4)  DECLW(5)  DECLW(6)  DECLW(7)
        DECLW(8)  DECLW(9)  DECLW(10) DECLW(11) DECLW(12) DECLW(13) DECLW(14) DECLW(15)
        DECLW(16) DECLW(17) DECLW(18) DECLW(19) DECLW(20) DECLW(21) DECLW(22) DECLW(23)
        DECLW(24) DECLW(25) DECLW(26) DECLW(27) DECLW(28) DECLW(29) DECLW(30) DECLW(31)

#define LOADW(i) { \
        const float* r0_ = &Whh[(size_t)(ks * 64 + 2 * i) * H_ + j0]; \
        const float* r1_ = r0_ + H_; \
        half2v v0_ = __builtin_amdgcn_cvt_pkrtz(r0_[0], r1_[0]); \
        half2v v1_ = __builtin_amdgcn_cvt_pkrtz(r0_[1], r1_[1]); \
        half2v v2_ = __builtin_amdgcn_cvt_pkrtz(r0_[2], r1_[2]); \
        half2v v3_ = __builtin_amdgcn_cvt_pkrtz(r0_[3], r1_[3]); \
        w##i##_0 = __builtin_bit_cast(int, v0_); \
        w##i##_1 = __builtin_bit_cast(int, v1_); \
        w##i##_2 = __builtin_bit_cast(int, v2_); \
        w##i##_3 = __builtin_bit_cast(int, v3_); \
        asm volatile("" : "+v"(w##i##_0), "+v"(w##i##_1), \
                          "+v"(w##i##_2), "+v"(w##i##_3)); \
    }
        LOADW(0)  LOADW(1)  LOADW(2)  LOADW(3)  LOADW(4)  LOADW(5)  LOADW(6)  LOADW(7)
        LOADW(8)  LOADW(9)  LOADW(10) LOADW(11) LOADW(12) LOADW(13) LOADW(14) LOADW(15)
        LOADW(16) LOADW(17) LOADW(18) LOADW(19) LOADW(20) LOADW(21) LOADW(22) LOADW(23)
        LOADW(24) LOADW(25) LOADW(26) LOADW(27) LOADW(28) LOADW(29) LOADW(30) LOADW(31)

        if (tid < 128) {
            half2v hp = __builtin_amdgcn_cvt_pkrtz(h[b * H_ + 2 * tid],
                                                   h[b * H_ + 2 * tid + 1]);
            // j = 2*tid: segment tid>>5, dword offset tid&31
            ((half2v*)hbuf)[(tid >> 5) * 36 + (tid & 31)] = hp;
        }
        float xpn = xp_cur[(size_t)b * H_ + jf];
        __syncthreads();

        int p = 0;
        const int rd_base = ks * 36;                       // dwords
        const int wr_idx  = (jg >> 4) * 36 + ((jg & 15) << 1);  // half2 slot
        for (int s = 0; s < steps; s++) {
            const float xpc = xpn;
            if (s + 1 < steps)
                xpn = xp_cur[((size_t)(s + 1) * B_ + b) * H_ + jf];

            // this lane's 64-value h segment: 8 x ds_read_b128 (broadcast x16)
            half2v hk[32];
            {
                const float4* hs = (const float4*)&hbuf[p * 144 + rd_base];
                #pragma unroll
                for (int t = 0; t < 8; t++)
                    *(float4*)&hk[t * 4] = hs[t];
            }

            // 128 fdot2: 4 outputs x 2 sub-chains of depth 16
            float pA0 = 0.f, pA1 = 0.f, pA2 = 0.f, pA3 = 0.f;
            float pB0 = 0.f, pB1 = 0.f, pB2 = 0.f, pB3 = 0.f;
#define DOTA(i) \
            pA0 = __builtin_amdgcn_fdot2(hk[i], __builtin_bit_cast(half2v, w##i##_0), pA0, false); \
            pA1 = __builtin_amdgcn_fdot2(hk[i], __builtin_bit_cast(half2v, w##i##_1), pA1, false); \
            pA2 = __builtin_amdgcn_fdot2(hk[i], __builtin_bit_cast(half2v, w##i##_2), pA2, false); \
            pA3 = __builtin_amdgcn_fdot2(hk[i], __builtin_bit_cast(half2v, w##i##_3), pA3, false);
#define DOTB(i) \
            pB0 = __builtin_amdgcn_fdot2(hk[i], __builtin_bit_cast(half2v, w##i##_0), pB0, false); \
            pB1 = __builtin_amdgcn_fdot2(hk[i], __builtin_bit_cast(half2v, w##i##_1), pB1, false); \
            pB2 = __builtin_amdgcn_fdot2(hk[i], __builtin_bit_cast(half2v, w##i##_2), pB2, false); \
            pB3 = __builtin_amdgcn_fdot2(hk[i], __builtin_bit_cast(half2v, w##i##_3), pB3, false);
            DOTA(0)  DOTA(1)  DOTA(2)  DOTA(3)  DOTA(4)  DOTA(5)  DOTA(6)  DOTA(7)
            DOTA(8)  DOTA(9)  DOTA(10) DOTA(11) DOTA(12) DOTA(13) DOTA(14) DOTA(15)
            DOTB(16) DOTB(17) DOTB(18) DOTB(19) DOTB(20) DOTB(21) DOTB(22) DOTB(23)
            DOTB(24) DOTB(25) DOTB(26) DOTB(27) DOTB(28) DOTB(29) DOTB(30) DOTB(31)

            const float acc0 = pA0 + pB0;            // partial(j0,   k-range ks)
            const float acc1 = pA1 + pB1;
            const float acc2 = pA2 + pB2;
            const float acc3 = pA3 + pB3;

            // split-butterfly over the 4 ks lanes, all DPP quad_perm:
            // round 1 (xor1): lo lane keeps outputs {0,1}, hi keeps {2,3}
            const bool b0 = (ks & 1), b1 = (ks & 2);
            float r0, r1;
            {
                float s0 = b0 ? acc0 : acc2;
                float s1 = b0 ? acc1 : acc3;
                r0 = (b0 ? acc2 : acc0) + dpp_xor1(s0);
                r1 = (b0 ? acc3 : acc1) + dpp_xor1(s1);
            }
            // round 2 (xor2): keep one output, full k
            float q;
            {
                float s2 = b1 ? r0 : r1;
                q = (b1 ? r1 : r0) + dpp_xor2(s2);
            }
            const float v = q + xpc;

            const float e2 = __expf(2.f * v);
            const float hn = 1.f - 2.f / (e2 + 1.f);   // tanh(v)

            // pack the quad's 4 outputs (lane order ks:{0,2,1,3} holds
            // jf-off {0,1,2,3} pairs) into lane ks==0 as a b64 write:
            //   slotA (off 0,1) = (hn@ks0, hn@ks2); slotB (off 2,3) = (hn@ks1, hn@ks3)
            const float from2 = dpp_xor2(hn);          // ks0<-ks2, ks1<-ks3
            half2v pk = __builtin_amdgcn_cvt_pkrtz(hn, from2);
            int pki = __builtin_bit_cast(int, pk);     // slotA on ks0, slotB on ks1
            int slotB = dpp_xor1_i(pki);               // ks0 <- ks1's pk
            if (ks == 0) {
                float2 wv;
                wv.x = __builtin_bit_cast(float, pki);
                wv.y = __builtin_bit_cast(float, slotB);
                *(float2*)&((half2v*)hbuf)[(p ^ 1) * 144 + wr_idx] = wv;
            }
            if (s == steps - 1) h[b * H_ + jf] = hn;   // fp32 carry-out, all lanes
            __syncthreads();
            p ^= 1;
        }
    } else if (A != nullptr) {
        // ---------------- gemm: xp_next = A @ Wih + bias (256 threads) -------
        float (*As)[68] = (float(*)[68])smem;
        float (*Bs)[64] = (float(*)[64])(smem + 32 * 68);

        const int gid = blockIdx.x - scan_blocks;
        const int bm = (gid >> 2) * 64;
        const int bn = (gid & 3) * 64;
        const int tx = tid & 15;
        const int ty = tid >> 4;

        float acc[4][4] = {};

        const int ar = tid >> 3;
        const int ak = (tid & 7) << 2;
        const int br = tid >> 4;
        const int bc = (tid & 15) << 2;

        for (int k0 = 0; k0 < E_; k0 += 32) {
            float4 a0 = *(const float4*)&A[(size_t)(bm + ar)      * E_ + k0 + ak];
            float4 a1 = *(const float4*)&A[(size_t)(bm + ar + 32) * E_ + k0 + ak];
            float4 bv0 = *(const float4*)&Wih[(size_t)(k0 + br)      * H_ + bn + bc];
            float4 bv1 = *(const float4*)&Wih[(size_t)(k0 + br + 16) * H_ + bn + bc];

            As[ak+0][ar]    = a0.x; As[ak+1][ar]    = a0.y; As[ak+2][ar]    = a0.z; As[ak+3][ar]    = a0.w;
            As[ak+0][ar+32] = a1.x; As[ak+1][ar+32] = a1.y; As[ak+2][ar+32] = a1.z; As[ak+3][ar+32] = a1.w;
            *(float4*)&Bs[br][bc]      = bv0;
            *(float4*)&Bs[br + 16][bc] = bv1;
            __syncthreads();

            #pragma unroll
            for (int kk = 0; kk < 32; kk++) {
                const float4 av = *(const float4*)&As[kk][ty << 2];
                const float4 bv = *(const float4*)&Bs[kk][tx << 2];
                acc[0][0] += av.x*bv.x; acc[0][1] += av.x*bv.y; acc[0][2] += av.x*bv.z; acc[0][3] += av.x*bv.w;
                acc[1][0] += av.y*bv.x; acc[1][1] += av.y*bv.y; acc[1][2] += av.y*bv.z; acc[1][3] += av.y*bv.w;
                acc[2][0] += av.z*bv.x; acc[2][1] += av.z*bv.y; acc[2][2] += av.z*bv.z; acc[2][3] += av.z*bv.w;
                acc[3][0] += av.w*bv.x; acc[3][1] += av.w*bv.y; acc[3][2] += av.w*bv.z; acc[3][3] += av.w*bv.w;
            }
            __syncthreads();
        }

        const float4 bb = *(const float4*)&bias[bn + (tx << 2)];
        #pragma unroll
        for (int i = 0; i < 4; i++) {
            float4 o;
            o.x = acc[i][0] + bb.x;
            o.y = acc[i][1] + bb.y;
            o.z = acc[i][2] + bb.z;
            o.w = acc[i][3] + bb.w;
            *(float4*)&xp_next[(size_t)(bm + (ty << 2) + i) * H_ + bn + (tx << 2)] = o;
        }
    }
}

extern "C" void kernel_launch(void* const* d_in, const int* in_sizes, int n_in,
                              void* d_out, int out_size, void* d_ws, size_t ws_size,
                              hipStream_t stream)
{
    const float* sentence = (const float*)d_in[0];  // [S,B,E]
    const float* h0       = (const float*)d_in[1];  // [B,H]
    const float* W_ih     = (const float*)d_in[2];  // [E,H]
    const float* W_hh     = (const float*)d_in[3];  // [H,H]
    const float* bias     = (const float*)d_in[4];  // [H]
    float* h  = (float*)d_out;
    float* ws = (float*)d_ws;

    // two ping-pong xp buffers, each [chunk*B, H]
    int chunk = 256;
    while ((size_t)2 * chunk * B_ * H_ * sizeof(float) > ws_size && chunk > 32)
        chunk >>= 1;
    const int nchunk = S_TOT / chunk;
    float* buf[2] = { ws, ws + (size_t)chunk * B_ * H_ };

    hipMemcpyAsync(h, h0, B_ * H_ * sizeof(float), hipMemcpyDeviceToDevice, stream);

    // pure gemm for chunk 0
    fused_step<<<chunk * 4, 256, 0, stream>>>(sentence, W_ih, bias, buf[0],
                                              nullptr, W_hh, h, 0, 0);
    for (int c = 0; c < nchunk; c++) {
        const bool last = (c == nchunk - 1);
        const int gemmb = last ? 0 : chunk * 4;
        const float* Anext = last ? nullptr
                                  : sentence + (size_t)(c + 1) * chunk * B_ * E_;
        fused_step<<<64 + gemmb, 256, 0, stream>>>(Anext, W_ih, bias,
                                                   buf[(c + 1) & 1],
                                                   buf[c & 1], W_hh, h,
                                                   chunk, 64);
    }
}